// Round 2
// baseline (2997.830 us; speedup 1.0000x reference)
//
#include <hip/hip_runtime.h>

typedef unsigned short ushortT;
typedef unsigned int uintT;
typedef __bf16 bf16x8 __attribute__((ext_vector_type(8)));
typedef float f32x4 __attribute__((ext_vector_type(4)));

#define B_ 16
#define N_ 8192
#define G_ 512
#define KNN_ 32
#define M_ (B_*G_)      // 8192 groups
#define R_ (M_*KNN_)    // 262144 rows

static __device__ __forceinline__ ushortT f2bf(float f){
  uintT u = __float_as_uint(f);
  return (ushortT)((u + 0x7fffu + ((u >> 16) & 1u)) >> 16);
}
static __device__ __forceinline__ float bf2f(ushortT h){ return __uint_as_float(((uintT)h) << 16); }

union U16 { uint4 u; ushortT s[8]; bf16x8 v; };

// ---------------- FPS: exact fp32 replication, 1 block per batch ----------------
__global__ __launch_bounds__(1024) void fps_kernel(const float* __restrict__ xyz,
                                                   float* __restrict__ center){
  const int b = blockIdx.x;
  const int tid = threadIdx.x;
  const float* P = xyz + (size_t)b * N_ * 3;
  float px[8], py[8], pz[8], dist[8];
#pragma unroll
  for (int k = 0; k < 8; k++){
    int p = tid + (k << 10);
    px[k] = P[p*3+0]; py[k] = P[p*3+1]; pz[k] = P[p*3+2];
    dist[k] = 1e10f;
  }
  __shared__ float s_val[16];
  __shared__ int   s_idx[16];
  __shared__ float s_cx, s_cy, s_cz;
  __shared__ int   s_far;
  if (tid == 0){ s_far = 0; s_cx = P[0]; s_cy = P[1]; s_cz = P[2]; }
  __syncthreads();
  const int lane = tid & 63, wid = tid >> 6;
  for (int s = 0; s < G_; s++){
    const float cx = s_cx, cy = s_cy, cz = s_cz;
    if (tid == 0){
      float* co = center + ((size_t)b * G_ + s) * 3;
      co[0] = cx; co[1] = cy; co[2] = cz;
    }
    float bv = -1.0f; int bi = 0;
#pragma unroll
    for (int k = 0; k < 8; k++){
      float d0 = __fsub_rn(px[k], cx), d1 = __fsub_rn(py[k], cy), d2 = __fsub_rn(pz[k], cz);
      float s0 = __fmul_rn(d0, d0), s1 = __fmul_rn(d1, d1), s2 = __fmul_rn(d2, d2);
      float d  = __fadd_rn(__fadd_rn(s0, s1), s2);
      float dd = fminf(dist[k], d);
      dist[k] = dd;
      if (dd > bv){ bv = dd; bi = tid + (k << 10); }
    }
#pragma unroll
    for (int m = 32; m >= 1; m >>= 1){
      float ov = __shfl_xor(bv, m); int oi = __shfl_xor(bi, m);
      if (ov > bv || (ov == bv && oi < bi)){ bv = ov; bi = oi; }
    }
    if (lane == 0){ s_val[wid] = bv; s_idx[wid] = bi; }
    __syncthreads();
    if (wid == 0){
      float v = (lane < 16) ? s_val[lane] : -1.0f;
      int   i = (lane < 16) ? s_idx[lane] : 0x7fffffff;
#pragma unroll
      for (int m = 8; m >= 1; m >>= 1){
        float ov = __shfl_xor(v, m); int oi = __shfl_xor(i, m);
        if (ov > v || (ov == v && oi < i)){ v = ov; i = oi; }
      }
      if (lane == 0) s_far = i;
    }
    __syncthreads();
    if (tid == (s_far & 1023)){
      int k = s_far >> 10;
      s_cx = px[k]; s_cy = py[k]; s_cz = pz[k];
    }
    __syncthreads();
  }
}

// ---------------- kNN: exact expanded-form distances, 32x argmin extraction ----------------
__global__ __launch_bounds__(256) void knn_kernel(const float* __restrict__ xyz,
                                                  const float* __restrict__ center,
                                                  int* __restrict__ knnIdx){
  const int mc = blockIdx.x;
  const int b  = mc >> 9;
  const int tid = threadIdx.x;
  const float* P = xyz + (size_t)b * N_ * 3;
  const float cx = center[mc*3+0], cy = center[mc*3+1], cz = center[mc*3+2];
  const float tc = __fadd_rn(__fadd_rn(__fmul_rn(cx,cx), __fmul_rn(cy,cy)), __fmul_rn(cz,cz));
  __shared__ float sd[N_];
  __shared__ float cv[256];
  __shared__ int   ci[256];
  __shared__ int   s_w;
  float bv = 1e30f; int bi = 0x7fffffff;
#pragma unroll 4
  for (int k = 0; k < 32; k++){
    int p = tid + (k << 8);
    float x = P[p*3+0], y = P[p*3+1], z = P[p*3+2];
    float tx  = __fadd_rn(__fadd_rn(__fmul_rn(x,x), __fmul_rn(y,y)), __fmul_rn(z,z));
    float dot = __fadd_rn(__fadd_rn(__fmul_rn(cx,x), __fmul_rn(cy,y)), __fmul_rn(cz,z));
    float d   = __fsub_rn(__fadd_rn(tc, tx), __fmul_rn(2.0f, dot));
    sd[p] = d;
    if (d < bv){ bv = d; bi = p; }
  }
  __syncthreads();
  for (int r = 0; r < KNN_; r++){
    cv[tid] = bv; ci[tid] = bi;
    __syncthreads();
    if (tid < 64){
      float v = cv[tid]; int i = ci[tid];
#pragma unroll
      for (int j = 1; j < 4; j++){
        float v2 = cv[tid + 64*j]; int i2 = ci[tid + 64*j];
        if (v2 < v || (v2 == v && i2 < i)){ v = v2; i = i2; }
      }
#pragma unroll
      for (int m = 32; m >= 1; m >>= 1){
        float ov = __shfl_xor(v, m); int oi = __shfl_xor(i, m);
        if (ov < v || (ov == v && oi < i)){ v = ov; i = oi; }
      }
      if (tid == 0){ s_w = i; knnIdx[(size_t)mc * KNN_ + r] = i; }
    }
    __syncthreads();
    int w = s_w;
    if (tid == (w & 255)){
      sd[w] = 1e30f;
      bv = 1e30f; bi = 0x7fffffff;
      for (int k = 0; k < 32; k++){
        int p = tid + (k << 8);
        float d = sd[p];
        if (d < bv){ bv = d; bi = p; }
      }
    }
    __syncthreads();
  }
}

// ---------------- moments: 9 spatial moments of gathered points (for BN1 analytic stats) ----
__global__ __launch_bounds__(256) void moments_kernel(const float* __restrict__ xyz,
                                                      const int* __restrict__ knnIdx,
                                                      float* __restrict__ Mpart){
  const int t = threadIdx.x, blk = blockIdx.x;
  float m[9];
#pragma unroll
  for (int k = 0; k < 9; k++) m[k] = 0.f;
  for (int i = 0; i < 4; i++){
    int row = blk * 1024 + i * 256 + t;
    int p = knnIdx[row];
    int b = row >> 14;
    const float* pt = xyz + ((size_t)(b * N_ + p)) * 3;
    float x = pt[0], y = pt[1], z = pt[2];
    m[0]+=x; m[1]+=y; m[2]+=z; m[3]+=x*x; m[4]+=y*y; m[5]+=z*z; m[6]+=x*y; m[7]+=x*z; m[8]+=y*z;
  }
  __shared__ float red[4][9];
  const int lane = t & 63, w = t >> 6;
#pragma unroll
  for (int k = 0; k < 9; k++){
    float v = m[k];
#pragma unroll
    for (int sh = 32; sh >= 1; sh >>= 1) v += __shfl_xor(v, sh);
    if (lane == 0) red[w][k] = v;
  }
  __syncthreads();
  if (t < 9) Mpart[blk * 9 + t] = red[0][t] + red[1][t] + red[2][t] + red[3][t];
}

// ---------------- prep1: BN1 stats analytically + fold into F1c ----------------
__global__ __launch_bounds__(128) void prep1_kernel(const float* __restrict__ Mpart,
                                                    const float* __restrict__ W1,
                                                    const float* __restrict__ b1,
                                                    const float* __restrict__ g1,
                                                    const float* __restrict__ be1,
                                                    float4* __restrict__ F1c){
  __shared__ float S[9];
  const int t = threadIdx.x;
  if (t < 9){
    float s = 0.f;
    for (int i = 0; i < 256; i++) s += Mpart[i * 9 + t];
    S[t] = s;
  }
  __syncthreads();
  const float invN = 1.0f / (float)R_;
  float mx = S[0]*invN, my = S[1]*invN, mz = S[2]*invN;
  float Cxx = S[3]*invN - mx*mx, Cyy = S[4]*invN - my*my, Czz = S[5]*invN - mz*mz;
  float Cxy = S[6]*invN - mx*my, Cxz = S[7]*invN - mx*mz, Cyz = S[8]*invN - my*mz;
  const int ch = t;
  float w0 = W1[ch*3+0], w1 = W1[ch*3+1], w2 = W1[ch*3+2], bb = b1[ch];
  float var = w0*w0*Cxx + w1*w1*Cyy + w2*w2*Czz + 2.f*(w0*w1*Cxy + w0*w2*Cxz + w1*w2*Cyz);
  float mu  = w0*mx + w1*my + w2*mz + bb;
  float sc  = rsqrtf(var + 1e-5f) * g1[ch];
  float sh  = be1[ch] - mu * sc;
  F1c[ch] = make_float4(w0*sc, w1*sc, w2*sc, fmaf(bb, sc, sh));
}

// ---------------- weight cast fp32 -> bf16 ----------------
__global__ __launch_bounds__(256) void cast3_kernel(const float* __restrict__ W2,
                                                    const float* __restrict__ W3,
                                                    const float* __restrict__ W4,
                                                    ushortT* W2b, ushortT* W3b, ushortT* W4b){
  int i = blockIdx.x * 256 + threadIdx.x;
  if (i < 32768)  W2b[i] = f2bf(W2[i]);
  if (i < 262144) W3b[i] = f2bf(W3[i]);
  if (i < 65536)  W4b[i] = f2bf(W4[i]);
}

// ---------------- per-lane layer-1 A fragments (no LDS): row r0, 4 x bf16x8 ----------------
static __device__ __forceinline__ void a1_frags(const float* __restrict__ xyz,
                                                const int* __restrict__ knnIdx,
                                                const float4* __restrict__ F1c,
                                                int row, int lg, bf16x8 fr[4]){
  const int p = knnIdx[row];
  const int b = row >> 14;
  const float* pt = xyz + ((size_t)(b * N_ + p)) * 3;
  const float x = pt[0], y = pt[1], z = pt[2];
#pragma unroll
  for (int s = 0; s < 4; s++){
    U16 u;
#pragma unroll
    for (int j = 0; j < 8; j++){
      const float4 f = F1c[s * 32 + lg * 8 + j];
      const float h = fmaxf(fmaf(x, f.x, fmaf(y, f.y, fmaf(z, f.z, f.w))), 0.f);
      u.s[j] = f2bf(h);
    }
    fr[s] = u.v;
  }
}

// ---------------- f2g: per-64-row tile, compute f2 (128x... 256 cols) and emit fg only ------
__global__ __launch_bounds__(256) void f2g_kernel(const float* __restrict__ xyz,
                                                  const int* __restrict__ knnIdx,
                                                  const float4* __restrict__ F1c,
                                                  const ushortT* __restrict__ W2bf,
                                                  const float* __restrict__ b2,
                                                  ushortT* __restrict__ fg){
  const int rc = blockIdx.x;                 // 4096 tiles of 64 rows
  const int t = threadIdx.x, lane = t & 63, w = t >> 6;
  const int lr = lane & 15, lg = lane >> 4;
  const int row = rc * 64 + w * 16 + lr;
  bf16x8 a1[4];
  a1_frags(xyz, knnIdx, F1c, row, lg, a1);
  f32x4 acc[16];
#pragma unroll
  for (int c = 0; c < 16; c++) acc[c] = (f32x4){0.f,0.f,0.f,0.f};
#pragma unroll
  for (int s = 0; s < 4; s++)
#pragma unroll
    for (int ct = 0; ct < 16; ct++){
      bf16x8 bb = *reinterpret_cast<const bf16x8*>(W2bf + (size_t)(ct*16+lr)*128 + s*32 + lg*8);
      acc[ct] = __builtin_amdgcn_mfma_f32_16x16x32_bf16(a1[s], bb, acc[ct], 0, 0, 0);
    }
  __shared__ float wmax[4][256];
#pragma unroll
  for (int ct = 0; ct < 16; ct++){
    float cmax = fmaxf(fmaxf(acc[ct][0], acc[ct][1]), fmaxf(acc[ct][2], acc[ct][3]));
    cmax = fmaxf(cmax, __shfl_xor(cmax, 16));
    cmax = fmaxf(cmax, __shfl_xor(cmax, 32));
    if (lg == 0) wmax[w][ct*16+lr] = cmax;
  }
  __syncthreads();
  {
    float bb = b2[t];
    fg[((size_t)rc*2 + 0)*256 + t] = f2bf(fmaxf(wmax[0][t], wmax[1][t]) + bb);
    fg[((size_t)rc*2 + 1)*256 + t] = f2bf(fmaxf(wmax[2][t], wmax[3][t]) + bb);
  }
}

// ---------------- u: U = fg @ W3a^T + b3 (8192 x 512, K=256), LDS-free ----------------
__global__ __launch_bounds__(256) void u_kernel(const ushortT* __restrict__ fg,
                                                const ushortT* __restrict__ W3bf,
                                                const float* __restrict__ b3,
                                                float* __restrict__ U){
  const int bid = blockIdx.x;                // 512 = 128 row-tiles x 4 col-chunks
  const int rc = bid >> 2, cc = bid & 3;
  const int t = threadIdx.x, lane = t & 63, w = t >> 6;
  const int lr = lane & 15, lg = lane >> 4;
  const int arow = rc * 64 + w * 16 + lr;
  f32x4 acc[8];
#pragma unroll
  for (int c = 0; c < 8; c++) acc[c] = (f32x4){0.f,0.f,0.f,0.f};
#pragma unroll
  for (int s = 0; s < 8; s++){
    bf16x8 a = *reinterpret_cast<const bf16x8*>(fg + (size_t)arow*256 + s*32 + lg*8);
#pragma unroll
    for (int ct = 0; ct < 8; ct++){
      bf16x8 bb = *reinterpret_cast<const bf16x8*>(W3bf + (size_t)(cc*128+ct*16+lr)*512 + s*32 + lg*8);
      acc[ct] = __builtin_amdgcn_mfma_f32_16x16x32_bf16(a, bb, acc[ct], 0, 0, 0);
    }
  }
#pragma unroll
  for (int ct = 0; ct < 8; ct++){
    int col = cc*128 + ct*16 + lr;
    float bb = b3[col];
#pragma unroll
    for (int i = 0; i < 4; i++){
      int crow = rc*64 + w*16 + lg*4 + i;
      U[(size_t)crow * 512 + col] = acc[ct][i] + bb;
    }
  }
}

// ---------------- f3c: recompute S2 into swizzled LDS, GEMM vs W3b, +U, stats, opt S3 store --
__global__ __launch_bounds__(256) void f3c_kernel(const float* __restrict__ xyz,
                                                  const int* __restrict__ knnIdx,
                                                  const float4* __restrict__ F1c,
                                                  const ushortT* __restrict__ W2bf,
                                                  const float* __restrict__ b2,
                                                  const ushortT* __restrict__ W3bf,
                                                  const float* __restrict__ U,
                                                  ushortT* __restrict__ S3,   // may be null
                                                  float* __restrict__ P2sum,
                                                  float* __restrict__ P2sq){
  __shared__ ushortT sS2[64 * 256];          // 32KB, XOR-swizzled
  __shared__ float ssum[4][128], ssq[4][128];
  const int rc = blockIdx.x;                 // 4096 tiles of 64 rows
  const size_t rows0 = (size_t)rc * 64;
  const int t = threadIdx.x, lane = t & 63, w = t >> 6;
  const int lr = lane & 15, lg = lane >> 4;
  const int r0l = w * 16 + lr;
  bf16x8 a1[4];
  a1_frags(xyz, knnIdx, F1c, rc*64 + r0l, lg, a1);
  // phase 1: S2 tile
#pragma unroll
  for (int half = 0; half < 2; half++){
    f32x4 acc[8];
#pragma unroll
    for (int c = 0; c < 8; c++) acc[c] = (f32x4){0.f,0.f,0.f,0.f};
#pragma unroll
    for (int s = 0; s < 4; s++)
#pragma unroll
      for (int ct = 0; ct < 8; ct++){
        bf16x8 bb = *reinterpret_cast<const bf16x8*>(W2bf + (size_t)(half*128+ct*16+lr)*128 + s*32 + lg*8);
        acc[ct] = __builtin_amdgcn_mfma_f32_16x16x32_bf16(a1[s], bb, acc[ct], 0, 0, 0);
      }
#pragma unroll
    for (int ct = 0; ct < 8; ct++){
      int col = half*128 + ct*16 + lr;
      float bb = b2[col];
#pragma unroll
      for (int i = 0; i < 4; i++){
        int rl = w*16 + lg*4 + i;
        sS2[rl * 256 + (col ^ ((rl & 7) << 3))] = f2bf(acc[ct][i] + bb);
      }
    }
  }
  __syncthreads();
  const int g = rc*2 + (w >> 1);
  // phase 2: 4 col-chunks of S3
  for (int chunk = 0; chunk < 4; chunk++){
    f32x4 acc[8];
#pragma unroll
    for (int c = 0; c < 8; c++) acc[c] = (f32x4){0.f,0.f,0.f,0.f};
#pragma unroll
    for (int s = 0; s < 8; s++){
      int k = s*32 + lg*8;
      bf16x8 a = *reinterpret_cast<const bf16x8*>(&sS2[r0l * 256 + (k ^ ((r0l & 7) << 3))]);
#pragma unroll
      for (int ct = 0; ct < 8; ct++){
        bf16x8 bb = *reinterpret_cast<const bf16x8*>(W3bf + (size_t)(chunk*128+ct*16+lr)*512 + 256 + k);
        acc[ct] = __builtin_amdgcn_mfma_f32_16x16x32_bf16(a, bb, acc[ct], 0, 0, 0);
      }
    }
#pragma unroll
    for (int ct = 0; ct < 8; ct++){
      int col = chunk*128 + ct*16 + lr;
      float uv = U[(size_t)g * 512 + col];
      float s = 0.f, q = 0.f;
#pragma unroll
      for (int i = 0; i < 4; i++){
        float val = acc[ct][i] + uv;
        if (S3){
          size_t row = rows0 + w*16 + lg*4 + i;
          S3[row * 512 + col] = f2bf(val);
        }
        s += val; q += val * val;
      }
      s += __shfl_xor(s, 16); s += __shfl_xor(s, 32);
      q += __shfl_xor(q, 16); q += __shfl_xor(q, 32);
      if (lg == 0){ ssum[w][ct*16+lr] = s; ssq[w][ct*16+lr] = q; }
    }
    __syncthreads();
    if (t < 128){
      float s = ssum[0][t] + ssum[1][t] + ssum[2][t] + ssum[3][t];
      float q = ssq[0][t] + ssq[1][t] + ssq[2][t] + ssq[3][t];
      P2sum[(size_t)rc * 512 + chunk*128 + t] = s;
      P2sq [(size_t)rc * 512 + chunk*128 + t] = q;
    }
    __syncthreads();
  }
}

// ---------------- BN finalize (BN2): one block per channel ----------------
__global__ __launch_bounds__(256) void fin_kernel(const float* __restrict__ Psum,
                                                  const float* __restrict__ Psq,
                                                  int nPart, int C, float invN,
                                                  const float* __restrict__ g,
                                                  const float* __restrict__ be,
                                                  float* __restrict__ scale,
                                                  float* __restrict__ shift){
  const int ch = blockIdx.x, t = threadIdx.x;
  float s = 0.f, q = 0.f;
  for (int i = t; i < nPart; i += 256){
    s += Psum[(size_t)i * C + ch];
    q += Psq [(size_t)i * C + ch];
  }
  __shared__ float ls[4], lq[4];
#pragma unroll
  for (int m = 32; m >= 1; m >>= 1){ s += __shfl_xor(s, m); q += __shfl_xor(q, m); }
  if ((t & 63) == 0){ ls[t >> 6] = s; lq[t >> 6] = q; }
  __syncthreads();
  if (t == 0){
    s = ls[0] + ls[1] + ls[2] + ls[3];
    q = lq[0] + lq[1] + lq[2] + lq[3];
    float mu = s * invN;
    float var = q * invN - mu * mu;
    float sc = rsqrtf(var + 1e-5f) * g[ch];
    scale[ch] = sc;
    shift[ch] = be[ch] - mu * sc;
  }
}

// ---------------- f4_full: reads stored S3, bn2+relu per-lane frags, GEMM W4, group-max -----
__global__ __launch_bounds__(256) void f4_full_kernel(const ushortT* __restrict__ S3,
                                                      const float* __restrict__ scale2,
                                                      const float* __restrict__ shift2,
                                                      const ushortT* __restrict__ W4bf,
                                                      const float* __restrict__ b4,
                                                      float* __restrict__ feat){
  __shared__ float s_sc[512], s_sh[512];
  __shared__ float wmax[4][128];
  const int rc = blockIdx.x;                 // 4096 tiles of 64 rows
  const int t = threadIdx.x, lane = t & 63, w = t >> 6;
  const int lr = lane & 15, lg = lane >> 4;
  for (int i = t; i < 512; i += 256){ s_sc[i] = scale2[i]; s_sh[i] = shift2[i]; }
  __syncthreads();
  const size_t arow = (size_t)rc * 64 + w * 16 + lr;
  f32x4 acc[8];
#pragma unroll
  for (int c = 0; c < 8; c++) acc[c] = (f32x4){0.f,0.f,0.f,0.f};
#pragma unroll
  for (int kq = 0; kq < 4; kq++)
#pragma unroll
    for (int s = 0; s < 4; s++){
      int k = kq*128 + s*32 + lg*8;
      U16 raw; raw.u = *reinterpret_cast<const uint4*>(S3 + arow * 512 + k);
      U16 hh;
#pragma unroll
      for (int j = 0; j < 8; j++){
        float v = bf2f(raw.s[j]);
        hh.s[j] = f2bf(fmaxf(fmaf(v, s_sc[k+j], s_sh[k+j]), 0.f));
      }
#pragma unroll
      for (int ct = 0; ct < 8; ct++){
        bf16x8 bb = *reinterpret_cast<const bf16x8*>(W4bf + (size_t)(ct*16+lr)*512 + k);
        acc[ct] = __builtin_amdgcn_mfma_f32_16x16x32_bf16(hh.v, bb, acc[ct], 0, 0, 0);
      }
    }
#pragma unroll
  for (int ct = 0; ct < 8; ct++){
    float cmax = fmaxf(fmaxf(acc[ct][0], acc[ct][1]), fmaxf(acc[ct][2], acc[ct][3]));
    cmax = fmaxf(cmax, __shfl_xor(cmax, 16));
    cmax = fmaxf(cmax, __shfl_xor(cmax, 32));
    if (lg == 0) wmax[w][ct*16+lr] = cmax;
  }
  __syncthreads();
  if (t < 256){
    int col = t & 127, gi = t >> 7;
    feat[((size_t)rc*2 + gi)*128 + col] =
      fmaxf(wmax[2*gi][col], wmax[2*gi+1][col]) + b4[col];
  }
}

// ---------------- f4_small: full recompute (a1 -> S2 LDS -> S3 chunks -> bn2relu -> W4) -----
__global__ __launch_bounds__(256) void f4_small_kernel(const float* __restrict__ xyz,
                                                       const int* __restrict__ knnIdx,
                                                       const float4* __restrict__ F1c,
                                                       const ushortT* __restrict__ W2bf,
                                                       const float* __restrict__ b2,
                                                       const ushortT* __restrict__ W3bf,
                                                       const float* __restrict__ U,
                                                       const float* __restrict__ scale2,
                                                       const float* __restrict__ shift2,
                                                       const ushortT* __restrict__ W4bf,
                                                       const float* __restrict__ b4,
                                                       float* __restrict__ feat){
  __shared__ ushortT sS2[64 * 256];          // 32KB swizzled
  __shared__ ushortT sAx[64 * 136];          // 17KB h-tile
  __shared__ float s_sc[512], s_sh[512];
  __shared__ float wmax[4][128];
  const int rc = blockIdx.x;
  const int t = threadIdx.x, lane = t & 63, w = t >> 6;
  const int lr = lane & 15, lg = lane >> 4;
  const int r0l = w * 16 + lr;
  for (int i = t; i < 512; i += 256){ s_sc[i] = scale2[i]; s_sh[i] = shift2[i]; }
  bf16x8 a1[4];
  a1_frags(xyz, knnIdx, F1c, rc*64 + r0l, lg, a1);
#pragma unroll
  for (int half = 0; half < 2; half++){
    f32x4 acc[8];
#pragma unroll
    for (int c = 0; c < 8; c++) acc[c] = (f32x4){0.f,0.f,0.f,0.f};
#pragma unroll
    for (int s = 0; s < 4; s++)
#pragma unroll
      for (int ct = 0; ct < 8; ct++){
        bf16x8 bb = *reinterpret_cast<const bf16x8*>(W2bf + (size_t)(half*128+ct*16+lr)*128 + s*32 + lg*8);
        acc[ct] = __builtin_amdgcn_mfma_f32_16x16x32_bf16(a1[s], bb, acc[ct], 0, 0, 0);
      }
#pragma unroll
    for (int ct = 0; ct < 8; ct++){
      int col = half*128 + ct*16 + lr;
      float bb = b2[col];
#pragma unroll
      for (int i = 0; i < 4; i++){
        int rl = w*16 + lg*4 + i;
        sS2[rl * 256 + (col ^ ((rl & 7) << 3))] = f2bf(acc[ct][i] + bb);
      }
    }
  }
  __syncthreads();
  const int g = rc*2 + (w >> 1);
  f32x4 accF4[8];
#pragma unroll
  for (int c = 0; c < 8; c++) accF4[c] = (f32x4){0.f,0.f,0.f,0.f};
  for (int chunk = 0; chunk < 4; chunk++){
    f32x4 acc[8];
#pragma unroll
    for (int c = 0; c < 8; c++) acc[c] = (f32x4){0.f,0.f,0.f,0.f};
#pragma unroll
    for (int s = 0; s < 8; s++){
      int k = s*32 + lg*8;
      bf16x8 a = *reinterpret_cast<const bf16x8*>(&sS2[r0l * 256 + (k ^ ((r0l & 7) << 3))]);
#pragma unroll
      for (int ct = 0; ct < 8; ct++){
        bf16x8 bb = *reinterpret_cast<const bf16x8*>(W3bf + (size_t)(chunk*128+ct*16+lr)*512 + 256 + k);
        acc[ct] = __builtin_amdgcn_mfma_f32_16x16x32_bf16(a, bb, acc[ct], 0, 0, 0);
      }
    }
    __syncthreads();   // previous chunk's f4-gemm finished reading sAx
#pragma unroll
    for (int ct = 0; ct < 8; ct++){
      int col = chunk*128 + ct*16 + lr;
      float uv = U[(size_t)g * 512 + col];
#pragma unroll
      for (int i = 0; i < 4; i++){
        int rl = w*16 + lg*4 + i;
        float val = acc[ct][i] + uv;
        sAx[rl * 136 + ct*16 + lr] = f2bf(fmaxf(fmaf(val, s_sc[col], s_sh[col]), 0.f));
      }
    }
    __syncthreads();
#pragma unroll
    for (int s = 0; s < 4; s++){
      bf16x8 a = *reinterpret_cast<const bf16x8*>(&sAx[r0l * 136 + s*32 + lg*8]);
#pragma unroll
      for (int ct = 0; ct < 8; ct++){
        bf16x8 bb = *reinterpret_cast<const bf16x8*>(W4bf + (size_t)(ct*16+lr)*512 + chunk*128 + s*32 + lg*8);
        accF4[ct] = __builtin_amdgcn_mfma_f32_16x16x32_bf16(a, bb, accF4[ct], 0, 0, 0);
      }
    }
  }
#pragma unroll
  for (int ct = 0; ct < 8; ct++){
    float cmax = fmaxf(fmaxf(accF4[ct][0], accF4[ct][1]), fmaxf(accF4[ct][2], accF4[ct][3]));
    cmax = fmaxf(cmax, __shfl_xor(cmax, 16));
    cmax = fmaxf(cmax, __shfl_xor(cmax, 32));
    if (lg == 0) wmax[w][ct*16+lr] = cmax;
  }
  __syncthreads();
  if (t < 256){
    int col = t & 127, gi = t >> 7;
    feat[((size_t)rc*2 + gi)*128 + col] =
      fmaxf(wmax[2*gi][col], wmax[2*gi+1][col]) + b4[col];
  }
}

extern "C" void kernel_launch(void* const* d_in, const int* in_sizes, int n_in,
                              void* d_out, int out_size, void* d_ws, size_t ws_size,
                              hipStream_t stream){
  const float* xyz = (const float*)d_in[0];
  const float* W1  = (const float*)d_in[1];
  const float* b1  = (const float*)d_in[2];
  const float* g1  = (const float*)d_in[3];
  const float* be1 = (const float*)d_in[4];
  const float* W2  = (const float*)d_in[5];
  const float* b2  = (const float*)d_in[6];
  const float* W3  = (const float*)d_in[7];
  const float* b3  = (const float*)d_in[8];
  const float* g2  = (const float*)d_in[9];
  const float* be2 = (const float*)d_in[10];
  const float* W4  = (const float*)d_in[11];
  const float* b4  = (const float*)d_in[12];

  float* out = (float*)d_out;
  float* center = out;                         // (16,512,3)
  float* feat   = out + (size_t)B_ * G_ * 3;   // (16,512,128)

  char* p = (char*)d_ws;
  size_t used = 0;
  auto alloc = [&](size_t bytes) -> char* {
    char* r = p + used; used += (bytes + 255) & ~(size_t)255; return r;
  };
  int*     knnIdx = (int*)    alloc((size_t)R_ * 4);           // 1 MB
  ushortT* W2bf   = (ushortT*)alloc(32768 * 2);
  ushortT* W3bf   = (ushortT*)alloc(262144 * 2);
  ushortT* W4bf   = (ushortT*)alloc(65536 * 2);
  float4*  F1c    = (float4*) alloc(128 * 16);
  float*   Mpart  = (float*)  alloc(256 * 9 * 4);
  ushortT* fg     = (ushortT*)alloc((size_t)M_ * 256 * 2);     // 4 MB
  float*   U      = (float*)  alloc((size_t)M_ * 512 * 4);     // 16 MB
  float*   P2sum  = (float*)  alloc((size_t)4096 * 512 * 4);   // 8 MB
  float*   P2sq   = (float*)  alloc((size_t)4096 * 512 * 4);   // 8 MB
  float*   scale2 = (float*)  alloc(512 * 4);
  float*   shift2 = (float*)  alloc(512 * 4);
  const size_t s3_bytes = (size_t)R_ * 512 * 2;                // 256 MB
  ushortT* S3 = nullptr;
  if (ws_size >= used + s3_bytes + 4096) S3 = (ushortT*)alloc(s3_bytes);

  cast3_kernel  <<<dim3(1024), dim3(256),  0, stream>>>(W2, W3, W4, W2bf, W3bf, W4bf);
  fps_kernel    <<<dim3(B_),   dim3(1024), 0, stream>>>(xyz, center);
  knn_kernel    <<<dim3(M_),   dim3(256),  0, stream>>>(xyz, center, knnIdx);
  moments_kernel<<<dim3(256),  dim3(256),  0, stream>>>(xyz, knnIdx, Mpart);
  prep1_kernel  <<<dim3(1),    dim3(128),  0, stream>>>(Mpart, W1, b1, g1, be1, F1c);
  f2g_kernel    <<<dim3(4096), dim3(256),  0, stream>>>(xyz, knnIdx, F1c, W2bf, b2, fg);
  u_kernel      <<<dim3(512),  dim3(256),  0, stream>>>(fg, W3bf, b3, U);
  f3c_kernel    <<<dim3(4096), dim3(256),  0, stream>>>(xyz, knnIdx, F1c, W2bf, b2, W3bf, U, S3, P2sum, P2sq);
  fin_kernel    <<<dim3(512),  dim3(256),  0, stream>>>(P2sum, P2sq, 4096, 512, 1.0f/(float)R_, g2, be2, scale2, shift2);
  if (S3)
    f4_full_kernel <<<dim3(4096), dim3(256), 0, stream>>>(S3, scale2, shift2, W4bf, b4, feat);
  else
    f4_small_kernel<<<dim3(4096), dim3(256), 0, stream>>>(xyz, knnIdx, F1c, W2bf, b2, W3bf, U,
                                                          scale2, shift2, W4bf, b4, feat);
}

// Round 3
// 2644.848 us; speedup vs baseline: 1.1335x; 1.1335x over previous
//
#include <hip/hip_runtime.h>

typedef unsigned short ushortT;
typedef unsigned int uintT;
typedef unsigned long long u64T;
typedef __bf16 bf16x8 __attribute__((ext_vector_type(8)));
typedef float f32x4 __attribute__((ext_vector_type(4)));

#define B_ 16
#define N_ 8192
#define G_ 512
#define KNN_ 32
#define M_ (B_*G_)      // 8192 groups
#define R_ (M_*KNN_)    // 262144 rows

static __device__ __forceinline__ ushortT f2bf(float f){
  uintT u = __float_as_uint(f);
  return (ushortT)((u + 0x7fffu + ((u >> 16) & 1u)) >> 16);
}
static __device__ __forceinline__ float bf2f(ushortT h){ return __uint_as_float(((uintT)h) << 16); }

union U16 { uint4 u; ushortT s[8]; bf16x8 v; };

// ---------------- FPS: exact fp32 replication, 1 block/batch, 1 barrier/step ----------------
// Points cached in LDS so the winning center's coords are read directly (broadcast) --
// no publish round-trip. Argmax via packed (distbits<<32)|~idx u64 max (first-index ties).
__global__ __launch_bounds__(1024) void fps_kernel(const float* __restrict__ xyz,
                                                   float* __restrict__ center){
  const int b = blockIdx.x;
  const int tid = threadIdx.x;
  const float* P = xyz + (size_t)b * N_ * 3;
  __shared__ float sx[N_], sy[N_], sz[N_];       // 96 KB
  __shared__ u64T slot[2][16];
  float px[8], py[8], pz[8], dist[8];
  uintT nI[8];
#pragma unroll
  for (int k = 0; k < 8; k++){
    int p = tid + (k << 10);
    float x = P[p*3+0], y = P[p*3+1], z = P[p*3+2];
    sx[p] = x; sy[p] = y; sz[p] = z;
    px[k] = x; py[k] = y; pz[k] = z;
    dist[k] = 1e10f;
    nI[k] = ~(uintT)p;
  }
  __syncthreads();
  const int lane = tid & 63, wid = tid >> 6;
  int far = 0;
  for (int s = 0; s < G_; s++){
    const float cx = sx[far], cy = sy[far], cz = sz[far];
    if (tid == 0){
      float* co = center + ((size_t)b * G_ + s) * 3;
      co[0] = cx; co[1] = cy; co[2] = cz;
    }
    u64T best = 0ull;
#pragma unroll
    for (int k = 0; k < 8; k++){
      float d0 = __fsub_rn(px[k], cx), d1 = __fsub_rn(py[k], cy), d2 = __fsub_rn(pz[k], cz);
      float d  = __fadd_rn(__fadd_rn(__fmul_rn(d0,d0), __fmul_rn(d1,d1)), __fmul_rn(d2,d2));
      float dd = fminf(dist[k], d);
      dist[k] = dd;
      u64T pk = ((u64T)__float_as_uint(dd) << 32) | nI[k];
      best = (pk > best) ? pk : best;
    }
#pragma unroll
    for (int m = 32; m >= 1; m >>= 1){
      u64T o = __shfl_xor(best, m);
      best = (o > best) ? o : best;
    }
    if (lane == 0) slot[s & 1][wid] = best;
    __syncthreads();
    u64T v = slot[s & 1][lane & 15];
#pragma unroll
    for (int m = 8; m >= 1; m >>= 1){
      u64T o = __shfl_xor(v, m);
      v = (o > v) ? o : v;
    }
    far = (int)(~(uintT)v);           // low word = ~p
  }
}

// ---------------- kNN: per-wave barrier-free extraction + single merge --------------------
// Exact expanded-form distances (_rn ops). Keys: monotone-mapped u32 dist (handles negative
// rounding artifacts) packed with point index for exact (dist, idx) lexicographic order.
__global__ __launch_bounds__(256) void knn_kernel(const float* __restrict__ xyz,
                                                  const float* __restrict__ center,
                                                  int* __restrict__ knnIdx){
  const int mc = blockIdx.x;
  const int b  = mc >> 9;
  const int tid = threadIdx.x;
  const int lane = tid & 63, w = tid >> 6;
  const float* P = xyz + (size_t)b * N_ * 3;
  const float cx = center[mc*3+0], cy = center[mc*3+1], cz = center[mc*3+2];
  const float tc = __fadd_rn(__fadd_rn(__fmul_rn(cx,cx), __fmul_rn(cy,cy)), __fmul_rn(cz,cz));
  uintT key[32];
  uintT bd = 0xFFFFFFFFu; int bk = 0;
#pragma unroll
  for (int k = 0; k < 32; k++){
    int p = tid + (k << 8);
    float x = P[p*3+0], y = P[p*3+1], z = P[p*3+2];
    float tx  = __fadd_rn(__fadd_rn(__fmul_rn(x,x), __fmul_rn(y,y)), __fmul_rn(z,z));
    float dot = __fadd_rn(__fadd_rn(__fmul_rn(cx,x), __fmul_rn(cy,y)), __fmul_rn(cz,z));
    float d   = __fsub_rn(__fadd_rn(tc, tx), __fmul_rn(2.0f, dot));
    uintT bb  = __float_as_uint(d);
    uintT kk  = bb ^ ((uintT)((int)bb >> 31) | 0x80000000u);   // monotone map
    key[k] = kk;
    if (kk < bd){ bd = kk; bk = k; }
  }
  __shared__ u64T sKeys[128];
  for (int r = 0; r < KNN_; r++){
    u64T me = ((u64T)bd << 32) | (uintT)(tid + (bk << 8));
    u64T m = me;
#pragma unroll
    for (int msk = 32; msk >= 1; msk >>= 1){
      u64T o = __shfl_xor(m, msk);
      m = (o < m) ? o : m;
    }
    if (lane == 0) sKeys[w * 32 + r] = m;
    if (me == m){                      // exactly one lane per wave (keys unique)
      uintT nb = 0xFFFFFFFFu; int nk = 0;
#pragma unroll
      for (int k = 0; k < 32; k++){    // static indices only (no scratch)
        uintT vv = (k == bk) ? 0xFFFFFFFFu : key[k];
        key[k] = vv;
        if (vv < nb){ nb = vv; nk = k; }
      }
      bd = nb; bk = nk;
    }
  }
  __syncthreads();
  if (w == 0){
    u64T e0 = sKeys[lane], e1 = sKeys[lane + 64];
    for (int r = 0; r < KNN_; r++){
      u64T be = (e0 < e1) ? e0 : e1;
      u64T m = be;
#pragma unroll
      for (int msk = 32; msk >= 1; msk >>= 1){
        u64T o = __shfl_xor(m, msk);
        m = (o < m) ? o : m;
      }
      if (lane == 0) knnIdx[(size_t)mc * KNN_ + r] = (int)(uintT)m;
      if (be == m){
        if (e0 == m) e0 = ~0ull; else e1 = ~0ull;
      }
    }
  }
}

// ---------------- moments: 9 spatial moments of gathered points (for BN1 analytic stats) ----
__global__ __launch_bounds__(256) void moments_kernel(const float* __restrict__ xyz,
                                                      const int* __restrict__ knnIdx,
                                                      float* __restrict__ Mpart){
  const int t = threadIdx.x, blk = blockIdx.x;
  float m[9];
#pragma unroll
  for (int k = 0; k < 9; k++) m[k] = 0.f;
  for (int i = 0; i < 4; i++){
    int row = blk * 1024 + i * 256 + t;
    int p = knnIdx[row];
    int b = row >> 14;
    const float* pt = xyz + ((size_t)(b * N_ + p)) * 3;
    float x = pt[0], y = pt[1], z = pt[2];
    m[0]+=x; m[1]+=y; m[2]+=z; m[3]+=x*x; m[4]+=y*y; m[5]+=z*z; m[6]+=x*y; m[7]+=x*z; m[8]+=y*z;
  }
  __shared__ float red[4][9];
  const int lane = t & 63, w = t >> 6;
#pragma unroll
  for (int k = 0; k < 9; k++){
    float v = m[k];
#pragma unroll
    for (int sh = 32; sh >= 1; sh >>= 1) v += __shfl_xor(v, sh);
    if (lane == 0) red[w][k] = v;
  }
  __syncthreads();
  if (t < 9) Mpart[blk * 9 + t] = red[0][t] + red[1][t] + red[2][t] + red[3][t];
}

// ---------------- prep1: BN1 stats analytically + fold into F1c ----------------
__global__ __launch_bounds__(128) void prep1_kernel(const float* __restrict__ Mpart,
                                                    const float* __restrict__ W1,
                                                    const float* __restrict__ b1,
                                                    const float* __restrict__ g1,
                                                    const float* __restrict__ be1,
                                                    float4* __restrict__ F1c){
  __shared__ float S[9];
  const int t = threadIdx.x;
  if (t < 9){
    float s = 0.f;
    for (int i = 0; i < 256; i++) s += Mpart[i * 9 + t];
    S[t] = s;
  }
  __syncthreads();
  const float invN = 1.0f / (float)R_;
  float mx = S[0]*invN, my = S[1]*invN, mz = S[2]*invN;
  float Cxx = S[3]*invN - mx*mx, Cyy = S[4]*invN - my*my, Czz = S[5]*invN - mz*mz;
  float Cxy = S[6]*invN - mx*my, Cxz = S[7]*invN - mx*mz, Cyz = S[8]*invN - my*mz;
  const int ch = t;
  float w0 = W1[ch*3+0], w1 = W1[ch*3+1], w2 = W1[ch*3+2], bb = b1[ch];
  float var = w0*w0*Cxx + w1*w1*Cyy + w2*w2*Czz + 2.f*(w0*w1*Cxy + w0*w2*Cxz + w1*w2*Cyz);
  float mu  = w0*mx + w1*my + w2*mz + bb;
  float sc  = rsqrtf(var + 1e-5f) * g1[ch];
  float sh  = be1[ch] - mu * sc;
  F1c[ch] = make_float4(w0*sc, w1*sc, w2*sc, fmaf(bb, sc, sh));
}

// ---------------- weight cast fp32 -> bf16 ----------------
__global__ __launch_bounds__(256) void cast3_kernel(const float* __restrict__ W2,
                                                    const float* __restrict__ W3,
                                                    const float* __restrict__ W4,
                                                    ushortT* W2b, ushortT* W3b, ushortT* W4b){
  int i = blockIdx.x * 256 + threadIdx.x;
  if (i < 32768)  W2b[i] = f2bf(W2[i]);
  if (i < 262144) W3b[i] = f2bf(W3[i]);
  if (i < 65536)  W4b[i] = f2bf(W4[i]);
}

// ---------------- per-lane layer-1 A fragments (no LDS): row r0, 4 x bf16x8 ----------------
static __device__ __forceinline__ void a1_frags(const float* __restrict__ xyz,
                                                const int* __restrict__ knnIdx,
                                                const float4* __restrict__ F1c,
                                                int row, int lg, bf16x8 fr[4]){
  const int p = knnIdx[row];
  const int b = row >> 14;
  const float* pt = xyz + ((size_t)(b * N_ + p)) * 3;
  const float x = pt[0], y = pt[1], z = pt[2];
#pragma unroll
  for (int s = 0; s < 4; s++){
    U16 u;
#pragma unroll
    for (int j = 0; j < 8; j++){
      const float4 f = F1c[s * 32 + lg * 8 + j];
      const float h = fmaxf(fmaf(x, f.x, fmaf(y, f.y, fmaf(z, f.z, f.w))), 0.f);
      u.s[j] = f2bf(h);
    }
    fr[s] = u.v;
  }
}

// ---------------- f2g: per-64-row tile, compute f2 (256 cols) and emit fg only ------
__global__ __launch_bounds__(256) void f2g_kernel(const float* __restrict__ xyz,
                                                  const int* __restrict__ knnIdx,
                                                  const float4* __restrict__ F1c,
                                                  const ushortT* __restrict__ W2bf,
                                                  const float* __restrict__ b2,
                                                  ushortT* __restrict__ fg){
  const int rc = blockIdx.x;                 // 4096 tiles of 64 rows
  const int t = threadIdx.x, lane = t & 63, w = t >> 6;
  const int lr = lane & 15, lg = lane >> 4;
  const int row = rc * 64 + w * 16 + lr;
  bf16x8 a1[4];
  a1_frags(xyz, knnIdx, F1c, row, lg, a1);
  f32x4 acc[16];
#pragma unroll
  for (int c = 0; c < 16; c++) acc[c] = (f32x4){0.f,0.f,0.f,0.f};
#pragma unroll
  for (int s = 0; s < 4; s++)
#pragma unroll
    for (int ct = 0; ct < 16; ct++){
      bf16x8 bb = *reinterpret_cast<const bf16x8*>(W2bf + (size_t)(ct*16+lr)*128 + s*32 + lg*8);
      acc[ct] = __builtin_amdgcn_mfma_f32_16x16x32_bf16(a1[s], bb, acc[ct], 0, 0, 0);
    }
  __shared__ float wmax[4][256];
#pragma unroll
  for (int ct = 0; ct < 16; ct++){
    float cmax = fmaxf(fmaxf(acc[ct][0], acc[ct][1]), fmaxf(acc[ct][2], acc[ct][3]));
    cmax = fmaxf(cmax, __shfl_xor(cmax, 16));
    cmax = fmaxf(cmax, __shfl_xor(cmax, 32));
    if (lg == 0) wmax[w][ct*16+lr] = cmax;
  }
  __syncthreads();
  {
    float bb = b2[t];
    fg[((size_t)rc*2 + 0)*256 + t] = f2bf(fmaxf(wmax[0][t], wmax[1][t]) + bb);
    fg[((size_t)rc*2 + 1)*256 + t] = f2bf(fmaxf(wmax[2][t], wmax[3][t]) + bb);
  }
}

// ---------------- u: U = fg @ W3a^T + b3 (8192 x 512, K=256), LDS-free ----------------
__global__ __launch_bounds__(256) void u_kernel(const ushortT* __restrict__ fg,
                                                const ushortT* __restrict__ W3bf,
                                                const float* __restrict__ b3,
                                                float* __restrict__ U){
  const int bid = blockIdx.x;                // 512 = 128 row-tiles x 4 col-chunks
  const int rc = bid >> 2, cc = bid & 3;
  const int t = threadIdx.x, lane = t & 63, w = t >> 6;
  const int lr = lane & 15, lg = lane >> 4;
  const int arow = rc * 64 + w * 16 + lr;
  f32x4 acc[8];
#pragma unroll
  for (int c = 0; c < 8; c++) acc[c] = (f32x4){0.f,0.f,0.f,0.f};
#pragma unroll
  for (int s = 0; s < 8; s++){
    bf16x8 a = *reinterpret_cast<const bf16x8*>(fg + (size_t)arow*256 + s*32 + lg*8);
#pragma unroll
    for (int ct = 0; ct < 8; ct++){
      bf16x8 bb = *reinterpret_cast<const bf16x8*>(W3bf + (size_t)(cc*128+ct*16+lr)*512 + s*32 + lg*8);
      acc[ct] = __builtin_amdgcn_mfma_f32_16x16x32_bf16(a, bb, acc[ct], 0, 0, 0);
    }
  }
#pragma unroll
  for (int ct = 0; ct < 8; ct++){
    int col = cc*128 + ct*16 + lr;
    float bb = b3[col];
#pragma unroll
    for (int i = 0; i < 4; i++){
      int crow = rc*64 + w*16 + lg*4 + i;
      U[(size_t)crow * 512 + col] = acc[ct][i] + bb;
    }
  }
}

// ---------------- f3c: recompute S2 into swizzled LDS, GEMM vs W3b, +U, stats, opt S3 store --
__global__ __launch_bounds__(256) void f3c_kernel(const float* __restrict__ xyz,
                                                  const int* __restrict__ knnIdx,
                                                  const float4* __restrict__ F1c,
                                                  const ushortT* __restrict__ W2bf,
                                                  const float* __restrict__ b2,
                                                  const ushortT* __restrict__ W3bf,
                                                  const float* __restrict__ U,
                                                  ushortT* __restrict__ S3,   // may be null
                                                  float* __restrict__ P2sum,
                                                  float* __restrict__ P2sq){
  __shared__ ushortT sS2[64 * 256];          // 32KB, XOR-swizzled
  __shared__ float ssum[4][128], ssq[4][128];
  const int rc = blockIdx.x;                 // 4096 tiles of 64 rows
  const size_t rows0 = (size_t)rc * 64;
  const int t = threadIdx.x, lane = t & 63, w = t >> 6;
  const int lr = lane & 15, lg = lane >> 4;
  const int r0l = w * 16 + lr;
  bf16x8 a1[4];
  a1_frags(xyz, knnIdx, F1c, rc*64 + r0l, lg, a1);
#pragma unroll
  for (int half = 0; half < 2; half++){
    f32x4 acc[8];
#pragma unroll
    for (int c = 0; c < 8; c++) acc[c] = (f32x4){0.f,0.f,0.f,0.f};
#pragma unroll
    for (int s = 0; s < 4; s++)
#pragma unroll
      for (int ct = 0; ct < 8; ct++){
        bf16x8 bb = *reinterpret_cast<const bf16x8*>(W2bf + (size_t)(half*128+ct*16+lr)*128 + s*32 + lg*8);
        acc[ct] = __builtin_amdgcn_mfma_f32_16x16x32_bf16(a1[s], bb, acc[ct], 0, 0, 0);
      }
#pragma unroll
    for (int ct = 0; ct < 8; ct++){
      int col = half*128 + ct*16 + lr;
      float bb = b2[col];
#pragma unroll
      for (int i = 0; i < 4; i++){
        int rl = w*16 + lg*4 + i;
        sS2[rl * 256 + (col ^ ((rl & 7) << 3))] = f2bf(acc[ct][i] + bb);
      }
    }
  }
  __syncthreads();
  const int g = rc*2 + (w >> 1);
  for (int chunk = 0; chunk < 4; chunk++){
    f32x4 acc[8];
#pragma unroll
    for (int c = 0; c < 8; c++) acc[c] = (f32x4){0.f,0.f,0.f,0.f};
#pragma unroll
    for (int s = 0; s < 8; s++){
      int k = s*32 + lg*8;
      bf16x8 a = *reinterpret_cast<const bf16x8*>(&sS2[r0l * 256 + (k ^ ((r0l & 7) << 3))]);
#pragma unroll
      for (int ct = 0; ct < 8; ct++){
        bf16x8 bb = *reinterpret_cast<const bf16x8*>(W3bf + (size_t)(chunk*128+ct*16+lr)*512 + 256 + k);
        acc[ct] = __builtin_amdgcn_mfma_f32_16x16x32_bf16(a, bb, acc[ct], 0, 0, 0);
      }
    }
#pragma unroll
    for (int ct = 0; ct < 8; ct++){
      int col = chunk*128 + ct*16 + lr;
      float uv = U[(size_t)g * 512 + col];
      float s = 0.f, q = 0.f;
#pragma unroll
      for (int i = 0; i < 4; i++){
        float val = acc[ct][i] + uv;
        if (S3){
          size_t row = rows0 + w*16 + lg*4 + i;
          S3[row * 512 + col] = f2bf(val);
        }
        s += val; q += val * val;
      }
      s += __shfl_xor(s, 16); s += __shfl_xor(s, 32);
      q += __shfl_xor(q, 16); q += __shfl_xor(q, 32);
      if (lg == 0){ ssum[w][ct*16+lr] = s; ssq[w][ct*16+lr] = q; }
    }
    __syncthreads();
    if (t < 128){
      float s = ssum[0][t] + ssum[1][t] + ssum[2][t] + ssum[3][t];
      float q = ssq[0][t] + ssq[1][t] + ssq[2][t] + ssq[3][t];
      P2sum[(size_t)rc * 512 + chunk*128 + t] = s;
      P2sq [(size_t)rc * 512 + chunk*128 + t] = q;
    }
    __syncthreads();
  }
}

// ---------------- BN finalize (BN2): one block per channel ----------------
__global__ __launch_bounds__(256) void fin_kernel(const float* __restrict__ Psum,
                                                  const float* __restrict__ Psq,
                                                  int nPart, int C, float invN,
                                                  const float* __restrict__ g,
                                                  const float* __restrict__ be,
                                                  float* __restrict__ scale,
                                                  float* __restrict__ shift){
  const int ch = blockIdx.x, t = threadIdx.x;
  float s = 0.f, q = 0.f;
  for (int i = t; i < nPart; i += 256){
    s += Psum[(size_t)i * C + ch];
    q += Psq [(size_t)i * C + ch];
  }
  __shared__ float ls[4], lq[4];
#pragma unroll
  for (int m = 32; m >= 1; m >>= 1){ s += __shfl_xor(s, m); q += __shfl_xor(q, m); }
  if ((t & 63) == 0){ ls[t >> 6] = s; lq[t >> 6] = q; }
  __syncthreads();
  if (t == 0){
    s = ls[0] + ls[1] + ls[2] + ls[3];
    q = lq[0] + lq[1] + lq[2] + lq[3];
    float mu = s * invN;
    float var = q * invN - mu * mu;
    float sc = rsqrtf(var + 1e-5f) * g[ch];
    scale[ch] = sc;
    shift[ch] = be[ch] - mu * sc;
  }
}

// ---------------- f4_full: reads stored S3, bn2+relu per-lane frags, GEMM W4, group-max -----
__global__ __launch_bounds__(256) void f4_full_kernel(const ushortT* __restrict__ S3,
                                                      const float* __restrict__ scale2,
                                                      const float* __restrict__ shift2,
                                                      const ushortT* __restrict__ W4bf,
                                                      const float* __restrict__ b4,
                                                      float* __restrict__ feat){
  __shared__ float s_sc[512], s_sh[512];
  __shared__ float wmax[4][128];
  const int rc = blockIdx.x;                 // 4096 tiles of 64 rows
  const int t = threadIdx.x, lane = t & 63, w = t >> 6;
  const int lr = lane & 15, lg = lane >> 4;
  for (int i = t; i < 512; i += 256){ s_sc[i] = scale2[i]; s_sh[i] = shift2[i]; }
  __syncthreads();
  const size_t arow = (size_t)rc * 64 + w * 16 + lr;
  f32x4 acc[8];
#pragma unroll
  for (int c = 0; c < 8; c++) acc[c] = (f32x4){0.f,0.f,0.f,0.f};
#pragma unroll
  for (int kq = 0; kq < 4; kq++)
#pragma unroll
    for (int s = 0; s < 4; s++){
      int k = kq*128 + s*32 + lg*8;
      U16 raw; raw.u = *reinterpret_cast<const uint4*>(S3 + arow * 512 + k);
      U16 hh;
#pragma unroll
      for (int j = 0; j < 8; j++){
        float v = bf2f(raw.s[j]);
        hh.s[j] = f2bf(fmaxf(fmaf(v, s_sc[k+j], s_sh[k+j]), 0.f));
      }
#pragma unroll
      for (int ct = 0; ct < 8; ct++){
        bf16x8 bb = *reinterpret_cast<const bf16x8*>(W4bf + (size_t)(ct*16+lr)*512 + k);
        acc[ct] = __builtin_amdgcn_mfma_f32_16x16x32_bf16(hh.v, bb, acc[ct], 0, 0, 0);
      }
    }
#pragma unroll
  for (int ct = 0; ct < 8; ct++){
    float cmax = fmaxf(fmaxf(acc[ct][0], acc[ct][1]), fmaxf(acc[ct][2], acc[ct][3]));
    cmax = fmaxf(cmax, __shfl_xor(cmax, 16));
    cmax = fmaxf(cmax, __shfl_xor(cmax, 32));
    if (lg == 0) wmax[w][ct*16+lr] = cmax;
  }
  __syncthreads();
  if (t < 256){
    int col = t & 127, gi = t >> 7;
    feat[((size_t)rc*2 + gi)*128 + col] =
      fmaxf(wmax[2*gi][col], wmax[2*gi+1][col]) + b4[col];
  }
}

// ---------------- f4_small: full recompute (a1 -> S2 LDS -> S3 chunks -> bn2relu -> W4) -----
__global__ __launch_bounds__(256) void f4_small_kernel(const float* __restrict__ xyz,
                                                       const int* __restrict__ knnIdx,
                                                       const float4* __restrict__ F1c,
                                                       const ushortT* __restrict__ W2bf,
                                                       const float* __restrict__ b2,
                                                       const ushortT* __restrict__ W3bf,
                                                       const float* __restrict__ U,
                                                       const float* __restrict__ scale2,
                                                       const float* __restrict__ shift2,
                                                       const ushortT* __restrict__ W4bf,
                                                       const float* __restrict__ b4,
                                                       float* __restrict__ feat){
  __shared__ ushortT sS2[64 * 256];          // 32KB swizzled
  __shared__ ushortT sAx[64 * 136];          // 17KB h-tile
  __shared__ float s_sc[512], s_sh[512];
  __shared__ float wmax[4][128];
  const int rc = blockIdx.x;
  const int t = threadIdx.x, lane = t & 63, w = t >> 6;
  const int lr = lane & 15, lg = lane >> 4;
  const int r0l = w * 16 + lr;
  for (int i = t; i < 512; i += 256){ s_sc[i] = scale2[i]; s_sh[i] = shift2[i]; }
  bf16x8 a1[4];
  a1_frags(xyz, knnIdx, F1c, rc*64 + r0l, lg, a1);
#pragma unroll
  for (int half = 0; half < 2; half++){
    f32x4 acc[8];
#pragma unroll
    for (int c = 0; c < 8; c++) acc[c] = (f32x4){0.f,0.f,0.f,0.f};
#pragma unroll
    for (int s = 0; s < 4; s++)
#pragma unroll
      for (int ct = 0; ct < 8; ct++){
        bf16x8 bb = *reinterpret_cast<const bf16x8*>(W2bf + (size_t)(half*128+ct*16+lr)*128 + s*32 + lg*8);
        acc[ct] = __builtin_amdgcn_mfma_f32_16x16x32_bf16(a1[s], bb, acc[ct], 0, 0, 0);
      }
#pragma unroll
    for (int ct = 0; ct < 8; ct++){
      int col = half*128 + ct*16 + lr;
      float bb = b2[col];
#pragma unroll
      for (int i = 0; i < 4; i++){
        int rl = w*16 + lg*4 + i;
        sS2[rl * 256 + (col ^ ((rl & 7) << 3))] = f2bf(acc[ct][i] + bb);
      }
    }
  }
  __syncthreads();
  const int g = rc*2 + (w >> 1);
  f32x4 accF4[8];
#pragma unroll
  for (int c = 0; c < 8; c++) accF4[c] = (f32x4){0.f,0.f,0.f,0.f};
  for (int chunk = 0; chunk < 4; chunk++){
    f32x4 acc[8];
#pragma unroll
    for (int c = 0; c < 8; c++) acc[c] = (f32x4){0.f,0.f,0.f,0.f};
#pragma unroll
    for (int s = 0; s < 8; s++){
      int k = s*32 + lg*8;
      bf16x8 a = *reinterpret_cast<const bf16x8*>(&sS2[r0l * 256 + (k ^ ((r0l & 7) << 3))]);
#pragma unroll
      for (int ct = 0; ct < 8; ct++){
        bf16x8 bb = *reinterpret_cast<const bf16x8*>(W3bf + (size_t)(chunk*128+ct*16+lr)*512 + 256 + k);
        acc[ct] = __builtin_amdgcn_mfma_f32_16x16x32_bf16(a, bb, acc[ct], 0, 0, 0);
      }
    }
    __syncthreads();
#pragma unroll
    for (int ct = 0; ct < 8; ct++){
      int col = chunk*128 + ct*16 + lr;
      float uv = U[(size_t)g * 512 + col];
#pragma unroll
      for (int i = 0; i < 4; i++){
        int rl = w*16 + lg*4 + i;
        float val = acc[ct][i] + uv;
        sAx[rl * 136 + ct*16 + lr] = f2bf(fmaxf(fmaf(val, s_sc[col], s_sh[col]), 0.f));
      }
    }
    __syncthreads();
#pragma unroll
    for (int s = 0; s < 4; s++){
      bf16x8 a = *reinterpret_cast<const bf16x8*>(&sAx[r0l * 136 + s*32 + lg*8]);
#pragma unroll
      for (int ct = 0; ct < 8; ct++){
        bf16x8 bb = *reinterpret_cast<const bf16x8*>(W4bf + (size_t)(ct*16+lr)*512 + chunk*128 + s*32 + lg*8);
        accF4[ct] = __builtin_amdgcn_mfma_f32_16x16x32_bf16(a, bb, accF4[ct], 0, 0, 0);
      }
    }
  }
#pragma unroll
  for (int ct = 0; ct < 8; ct++){
    float cmax = fmaxf(fmaxf(accF4[ct][0], accF4[ct][1]), fmaxf(accF4[ct][2], accF4[ct][3]));
    cmax = fmaxf(cmax, __shfl_xor(cmax, 16));
    cmax = fmaxf(cmax, __shfl_xor(cmax, 32));
    if (lg == 0) wmax[w][ct*16+lr] = cmax;
  }
  __syncthreads();
  if (t < 256){
    int col = t & 127, gi = t >> 7;
    feat[((size_t)rc*2 + gi)*128 + col] =
      fmaxf(wmax[2*gi][col], wmax[2*gi+1][col]) + b4[col];
  }
}

extern "C" void kernel_launch(void* const* d_in, const int* in_sizes, int n_in,
                              void* d_out, int out_size, void* d_ws, size_t ws_size,
                              hipStream_t stream){
  const float* xyz = (const float*)d_in[0];
  const float* W1  = (const float*)d_in[1];
  const float* b1  = (const float*)d_in[2];
  const float* g1  = (const float*)d_in[3];
  const float* be1 = (const float*)d_in[4];
  const float* W2  = (const float*)d_in[5];
  const float* b2  = (const float*)d_in[6];
  const float* W3  = (const float*)d_in[7];
  const float* b3  = (const float*)d_in[8];
  const float* g2  = (const float*)d_in[9];
  const float* be2 = (const float*)d_in[10];
  const float* W4  = (const float*)d_in[11];
  const float* b4  = (const float*)d_in[12];

  float* out = (float*)d_out;
  float* center = out;                         // (16,512,3)
  float* feat   = out + (size_t)B_ * G_ * 3;   // (16,512,128)

  char* p = (char*)d_ws;
  size_t used = 0;
  auto alloc = [&](size_t bytes) -> char* {
    char* r = p + used; used += (bytes + 255) & ~(size_t)255; return r;
  };
  int*     knnIdx = (int*)    alloc((size_t)R_ * 4);           // 1 MB
  ushortT* W2bf   = (ushortT*)alloc(32768 * 2);
  ushortT* W3bf   = (ushortT*)alloc(262144 * 2);
  ushortT* W4bf   = (ushortT*)alloc(65536 * 2);
  float4*  F1c    = (float4*) alloc(128 * 16);
  float*   Mpart  = (float*)  alloc(256 * 9 * 4);
  ushortT* fg     = (ushortT*)alloc((size_t)M_ * 256 * 2);     // 4 MB
  float*   U      = (float*)  alloc((size_t)M_ * 512 * 4);     // 16 MB
  float*   P2sum  = (float*)  alloc((size_t)4096 * 512 * 4);   // 8 MB
  float*   P2sq   = (float*)  alloc((size_t)4096 * 512 * 4);   // 8 MB
  float*   scale2 = (float*)  alloc(512 * 4);
  float*   shift2 = (float*)  alloc(512 * 4);
  const size_t s3_bytes = (size_t)R_ * 512 * 2;                // 256 MB
  ushortT* S3 = nullptr;
  if (ws_size >= used + s3_bytes + 4096) S3 = (ushortT*)alloc(s3_bytes);

  cast3_kernel  <<<dim3(1024), dim3(256),  0, stream>>>(W2, W3, W4, W2bf, W3bf, W4bf);
  fps_kernel    <<<dim3(B_),   dim3(1024), 0, stream>>>(xyz, center);
  knn_kernel    <<<dim3(M_),   dim3(256),  0, stream>>>(xyz, center, knnIdx);
  moments_kernel<<<dim3(256),  dim3(256),  0, stream>>>(xyz, knnIdx, Mpart);
  prep1_kernel  <<<dim3(1),    dim3(128),  0, stream>>>(Mpart, W1, b1, g1, be1, F1c);
  f2g_kernel    <<<dim3(4096), dim3(256),  0, stream>>>(xyz, knnIdx, F1c, W2bf, b2, fg);
  u_kernel      <<<dim3(512),  dim3(256),  0, stream>>>(fg, W3bf, b3, U);
  f3c_kernel    <<<dim3(4096), dim3(256),  0, stream>>>(xyz, knnIdx, F1c, W2bf, b2, W3bf, U, S3, P2sum, P2sq);
  fin_kernel    <<<dim3(512),  dim3(256),  0, stream>>>(P2sum, P2sq, 4096, 512, 1.0f/(float)R_, g2, be2, scale2, shift2);
  if (S3)
    f4_full_kernel <<<dim3(4096), dim3(256), 0, stream>>>(S3, scale2, shift2, W4bf, b4, feat);
  else
    f4_small_kernel<<<dim3(4096), dim3(256), 0, stream>>>(xyz, knnIdx, F1c, W2bf, b2, W3bf, U,
                                                          scale2, shift2, W4bf, b4, feat);
}

// Round 4
// 1712.942 us; speedup vs baseline: 1.7501x; 1.5440x over previous
//
#include <hip/hip_runtime.h>

typedef unsigned short ushortT;
typedef unsigned int uintT;
typedef unsigned long long u64T;
typedef __bf16 bf16x8 __attribute__((ext_vector_type(8)));
typedef float f32x4 __attribute__((ext_vector_type(4)));

#define B_ 16
#define N_ 8192
#define G_ 512
#define KNN_ 32
#define M_ (B_*G_)      // 8192 groups
#define R_ (M_*KNN_)    // 262144 rows

static __device__ __forceinline__ ushortT f2bf(float f){
  uintT u = __float_as_uint(f);
  return (ushortT)((u + 0x7fffu + ((u >> 16) & 1u)) >> 16);
}
static __device__ __forceinline__ float bf2f(ushortT h){ return __uint_as_float(((uintT)h) << 16); }

union U16 { uint4 u; ushortT s[8]; bf16x8 v; };

// ---------------- FPS: exact fp32 replication, 1 block/batch, 1 barrier/step ----------------
__global__ __launch_bounds__(1024) void fps_kernel(const float* __restrict__ xyz,
                                                   float* __restrict__ center){
  const int b = blockIdx.x;
  const int tid = threadIdx.x;
  const float* P = xyz + (size_t)b * N_ * 3;
  __shared__ float sx[N_], sy[N_], sz[N_];       // 96 KB
  __shared__ u64T slot[2][16];
  float px[8], py[8], pz[8], dist[8];
  uintT nI[8];
#pragma unroll
  for (int k = 0; k < 8; k++){
    int p = tid + (k << 10);
    float x = P[p*3+0], y = P[p*3+1], z = P[p*3+2];
    sx[p] = x; sy[p] = y; sz[p] = z;
    px[k] = x; py[k] = y; pz[k] = z;
    dist[k] = 1e10f;
    nI[k] = ~(uintT)p;
  }
  __syncthreads();
  const int lane = tid & 63, wid = tid >> 6;
  int far = 0;
  for (int s = 0; s < G_; s++){
    const float cx = sx[far], cy = sy[far], cz = sz[far];
    if (tid == 0){
      float* co = center + ((size_t)b * G_ + s) * 3;
      co[0] = cx; co[1] = cy; co[2] = cz;
    }
    u64T best = 0ull;
#pragma unroll
    for (int k = 0; k < 8; k++){
      float d0 = __fsub_rn(px[k], cx), d1 = __fsub_rn(py[k], cy), d2 = __fsub_rn(pz[k], cz);
      float d  = __fadd_rn(__fadd_rn(__fmul_rn(d0,d0), __fmul_rn(d1,d1)), __fmul_rn(d2,d2));
      float dd = fminf(dist[k], d);
      dist[k] = dd;
      u64T pk = ((u64T)__float_as_uint(dd) << 32) | nI[k];
      best = (pk > best) ? pk : best;
    }
#pragma unroll
    for (int m = 32; m >= 1; m >>= 1){
      u64T o = __shfl_xor(best, m);
      best = (o > best) ? o : best;
    }
    if (lane == 0) slot[s & 1][wid] = best;
    __syncthreads();
    u64T v = slot[s & 1][lane & 15];
#pragma unroll
    for (int m = 8; m >= 1; m >>= 1){
      u64T o = __shfl_xor(v, m);
      v = (o > v) ? o : v;
    }
    far = (int)(~(uintT)v);
  }
}

// ---------------- kNN: per-wave barrier-free extraction + single merge --------------------
__global__ __launch_bounds__(256) void knn_kernel(const float* __restrict__ xyz,
                                                  const float* __restrict__ center,
                                                  int* __restrict__ knnIdx){
  const int mc = blockIdx.x;
  const int b  = mc >> 9;
  const int tid = threadIdx.x;
  const int lane = tid & 63, w = tid >> 6;
  const float* P = xyz + (size_t)b * N_ * 3;
  const float cx = center[mc*3+0], cy = center[mc*3+1], cz = center[mc*3+2];
  const float tc = __fadd_rn(__fadd_rn(__fmul_rn(cx,cx), __fmul_rn(cy,cy)), __fmul_rn(cz,cz));
  uintT key[32];
  uintT bd = 0xFFFFFFFFu; int bk = 0;
#pragma unroll
  for (int k = 0; k < 32; k++){
    int p = tid + (k << 8);
    float x = P[p*3+0], y = P[p*3+1], z = P[p*3+2];
    float tx  = __fadd_rn(__fadd_rn(__fmul_rn(x,x), __fmul_rn(y,y)), __fmul_rn(z,z));
    float dot = __fadd_rn(__fadd_rn(__fmul_rn(cx,x), __fmul_rn(cy,y)), __fmul_rn(cz,z));
    float d   = __fsub_rn(__fadd_rn(tc, tx), __fmul_rn(2.0f, dot));
    uintT bb  = __float_as_uint(d);
    uintT kk  = bb ^ ((uintT)((int)bb >> 31) | 0x80000000u);   // monotone map
    key[k] = kk;
    if (kk < bd){ bd = kk; bk = k; }
  }
  __shared__ u64T sKeys[128];
  for (int r = 0; r < KNN_; r++){
    u64T me = ((u64T)bd << 32) | (uintT)(tid + (bk << 8));
    u64T m = me;
#pragma unroll
    for (int msk = 32; msk >= 1; msk >>= 1){
      u64T o = __shfl_xor(m, msk);
      m = (o < m) ? o : m;
    }
    if (lane == 0) sKeys[w * 32 + r] = m;
    if (me == m){
      uintT nb = 0xFFFFFFFFu; int nk = 0;
#pragma unroll
      for (int k = 0; k < 32; k++){
        uintT vv = (k == bk) ? 0xFFFFFFFFu : key[k];
        key[k] = vv;
        if (vv < nb){ nb = vv; nk = k; }
      }
      bd = nb; bk = nk;
    }
  }
  __syncthreads();
  if (w == 0){
    u64T e0 = sKeys[lane], e1 = sKeys[lane + 64];
    for (int r = 0; r < KNN_; r++){
      u64T be = (e0 < e1) ? e0 : e1;
      u64T m = be;
#pragma unroll
      for (int msk = 32; msk >= 1; msk >>= 1){
        u64T o = __shfl_xor(m, msk);
        m = (o < m) ? o : m;
      }
      if (lane == 0) knnIdx[(size_t)mc * KNN_ + r] = (int)(uintT)m;
      if (be == m){
        if (e0 == m) e0 = ~0ull; else e1 = ~0ull;
      }
    }
  }
}

// ---------------- moments: 9 spatial moments of gathered points (BN1 analytic stats) ----
__global__ __launch_bounds__(256) void moments_kernel(const float* __restrict__ xyz,
                                                      const int* __restrict__ knnIdx,
                                                      float* __restrict__ Mpart){
  const int t = threadIdx.x, blk = blockIdx.x;
  float m[9];
#pragma unroll
  for (int k = 0; k < 9; k++) m[k] = 0.f;
  for (int i = 0; i < 4; i++){
    int row = blk * 1024 + i * 256 + t;
    int p = knnIdx[row];
    int b = row >> 14;
    const float* pt = xyz + ((size_t)(b * N_ + p)) * 3;
    float x = pt[0], y = pt[1], z = pt[2];
    m[0]+=x; m[1]+=y; m[2]+=z; m[3]+=x*x; m[4]+=y*y; m[5]+=z*z; m[6]+=x*y; m[7]+=x*z; m[8]+=y*z;
  }
  __shared__ float red[4][9];
  const int lane = t & 63, w = t >> 6;
#pragma unroll
  for (int k = 0; k < 9; k++){
    float v = m[k];
#pragma unroll
    for (int sh = 32; sh >= 1; sh >>= 1) v += __shfl_xor(v, sh);
    if (lane == 0) red[w][k] = v;
  }
  __syncthreads();
  if (t < 9) Mpart[blk * 9 + t] = red[0][t] + red[1][t] + red[2][t] + red[3][t];
}

// ---------------- prep1: BN1 stats analytically + fold into F1c ----------------
__global__ __launch_bounds__(128) void prep1_kernel(const float* __restrict__ Mpart,
                                                    const float* __restrict__ W1,
                                                    const float* __restrict__ b1,
                                                    const float* __restrict__ g1,
                                                    const float* __restrict__ be1,
                                                    float4* __restrict__ F1c){
  __shared__ float S[9];
  const int t = threadIdx.x;
  if (t < 9){
    float s = 0.f;
    for (int i = 0; i < 256; i++) s += Mpart[i * 9 + t];
    S[t] = s;
  }
  __syncthreads();
  const float invN = 1.0f / (float)R_;
  float mx = S[0]*invN, my = S[1]*invN, mz = S[2]*invN;
  float Cxx = S[3]*invN - mx*mx, Cyy = S[4]*invN - my*my, Czz = S[5]*invN - mz*mz;
  float Cxy = S[6]*invN - mx*my, Cxz = S[7]*invN - mx*mz, Cyz = S[8]*invN - my*mz;
  const int ch = t;
  float w0 = W1[ch*3+0], w1 = W1[ch*3+1], w2 = W1[ch*3+2], bb = b1[ch];
  float var = w0*w0*Cxx + w1*w1*Cyy + w2*w2*Czz + 2.f*(w0*w1*Cxy + w0*w2*Cxz + w1*w2*Cyz);
  float mu  = w0*mx + w1*my + w2*mz + bb;
  float sc  = rsqrtf(var + 1e-5f) * g1[ch];
  float sh  = be1[ch] - mu * sc;
  F1c[ch] = make_float4(w0*sc, w1*sc, w2*sc, fmaf(bb, sc, sh));
}

// ---------------- weight cast fp32 -> bf16 ----------------
__global__ __launch_bounds__(256) void cast3_kernel(const float* __restrict__ W2,
                                                    const float* __restrict__ W3,
                                                    const float* __restrict__ W4,
                                                    ushortT* W2b, ushortT* W3b, ushortT* W4b){
  int i = blockIdx.x * 256 + threadIdx.x;
  if (i < 32768)  W2b[i] = f2bf(W2[i]);
  if (i < 262144) W3b[i] = f2bf(W3[i]);
  if (i < 65536)  W4b[i] = f2bf(W4[i]);
}

// ---------------- per-lane layer-1 A fragments (no LDS): 4 x bf16x8 ----------------
static __device__ __forceinline__ void a1_frags(const float* __restrict__ xyz,
                                                const int* __restrict__ knnIdx,
                                                const float4* __restrict__ F1c,
                                                int row, int lg, bf16x8 fr[4]){
  const int p = knnIdx[row];
  const int b = row >> 14;
  const float* pt = xyz + ((size_t)(b * N_ + p)) * 3;
  const float x = pt[0], y = pt[1], z = pt[2];
#pragma unroll
  for (int s = 0; s < 4; s++){
    U16 u;
#pragma unroll
    for (int j = 0; j < 8; j++){
      const float4 f = F1c[s * 32 + lg * 8 + j];
      const float h = fmaxf(fmaf(x, f.x, fmaf(y, f.y, fmaf(z, f.z, f.w))), 0.f);
      u.s[j] = f2bf(h);
    }
    fr[s] = u.v;
  }
}

// ---------------- f2g: per-64-row tile, compute f2 (256 cols) and emit fg only ------
__global__ __launch_bounds__(256) void f2g_kernel(const float* __restrict__ xyz,
                                                  const int* __restrict__ knnIdx,
                                                  const float4* __restrict__ F1c,
                                                  const ushortT* __restrict__ W2bf,
                                                  const float* __restrict__ b2,
                                                  ushortT* __restrict__ fg){
  const int rc = blockIdx.x;                 // 4096 tiles of 64 rows
  const int t = threadIdx.x, lane = t & 63, w = t >> 6;
  const int lr = lane & 15, lg = lane >> 4;
  const int row = rc * 64 + w * 16 + lr;
  bf16x8 a1[4];
  a1_frags(xyz, knnIdx, F1c, row, lg, a1);
  f32x4 acc[16];
#pragma unroll
  for (int c = 0; c < 16; c++) acc[c] = (f32x4){0.f,0.f,0.f,0.f};
#pragma unroll
  for (int s = 0; s < 4; s++)
#pragma unroll
    for (int ct = 0; ct < 16; ct++){
      bf16x8 bb = *reinterpret_cast<const bf16x8*>(W2bf + (size_t)(ct*16+lr)*128 + s*32 + lg*8);
      acc[ct] = __builtin_amdgcn_mfma_f32_16x16x32_bf16(a1[s], bb, acc[ct], 0, 0, 0);
    }
  __shared__ float wmax[4][256];
#pragma unroll
  for (int ct = 0; ct < 16; ct++){
    float cmax = fmaxf(fmaxf(acc[ct][0], acc[ct][1]), fmaxf(acc[ct][2], acc[ct][3]));
    cmax = fmaxf(cmax, __shfl_xor(cmax, 16));
    cmax = fmaxf(cmax, __shfl_xor(cmax, 32));
    if (lg == 0) wmax[w][ct*16+lr] = cmax;
  }
  __syncthreads();
  {
    float bb = b2[t];
    fg[((size_t)rc*2 + 0)*256 + t] = f2bf(fmaxf(wmax[0][t], wmax[1][t]) + bb);
    fg[((size_t)rc*2 + 1)*256 + t] = f2bf(fmaxf(wmax[2][t], wmax[3][t]) + bb);
  }
}

// ---------------- u: U = fg @ W3a^T + b3 (8192 x 512, K=256), LDS-free ----------------
__global__ __launch_bounds__(256) void u_kernel(const ushortT* __restrict__ fg,
                                                const ushortT* __restrict__ W3bf,
                                                const float* __restrict__ b3,
                                                float* __restrict__ U){
  const int bid = blockIdx.x;                // 512 = 128 row-tiles x 4 col-chunks
  const int rc = bid >> 2, cc = bid & 3;
  const int t = threadIdx.x, lane = t & 63, w = t >> 6;
  const int lr = lane & 15, lg = lane >> 4;
  const int arow = rc * 64 + w * 16 + lr;
  f32x4 acc[8];
#pragma unroll
  for (int c = 0; c < 8; c++) acc[c] = (f32x4){0.f,0.f,0.f,0.f};
#pragma unroll
  for (int s = 0; s < 8; s++){
    bf16x8 a = *reinterpret_cast<const bf16x8*>(fg + (size_t)arow*256 + s*32 + lg*8);
#pragma unroll
    for (int ct = 0; ct < 8; ct++){
      bf16x8 bb = *reinterpret_cast<const bf16x8*>(W3bf + (size_t)(cc*128+ct*16+lr)*512 + s*32 + lg*8);
      acc[ct] = __builtin_amdgcn_mfma_f32_16x16x32_bf16(a, bb, acc[ct], 0, 0, 0);
    }
  }
#pragma unroll
  for (int ct = 0; ct < 8; ct++){
    int col = cc*128 + ct*16 + lr;
    float bb = b3[col];
#pragma unroll
    for (int i = 0; i < 4; i++){
      int crow = rc*64 + w*16 + lg*4 + i;
      U[(size_t)crow * 512 + col] = acc[ct][i] + bb;
    }
  }
}

// ====== shared phase A: compute S2 tile (128 rows x 256 cols) into swizzled LDS ======
// 8 waves, wave wv computes rows wv*16..wv*16+15 (all 256 cols).
static __device__ __forceinline__ void phaseA_s2(const float* __restrict__ xyz,
                                                 const int* __restrict__ knnIdx,
                                                 const float4* __restrict__ F1c,
                                                 const ushortT* __restrict__ W2bf,
                                                 const float* __restrict__ b2,
                                                 ushortT* sS2, int blk,
                                                 int wv, int lr, int lg){
  bf16x8 a1[4];
  a1_frags(xyz, knnIdx, F1c, blk*128 + wv*16 + lr, lg, a1);
  f32x4 acc[16];
#pragma unroll
  for (int c = 0; c < 16; c++) acc[c] = (f32x4){0.f,0.f,0.f,0.f};
#pragma unroll
  for (int s = 0; s < 4; s++)
#pragma unroll
    for (int ct = 0; ct < 16; ct++){
      bf16x8 bb = *reinterpret_cast<const bf16x8*>(W2bf + (size_t)(ct*16+lr)*128 + s*32 + lg*8);
      acc[ct] = __builtin_amdgcn_mfma_f32_16x16x32_bf16(a1[s], bb, acc[ct], 0, 0, 0);
    }
#pragma unroll
  for (int ct = 0; ct < 16; ct++){
    int col = ct*16 + lr;
    float bb = b2[col];
#pragma unroll
    for (int i = 0; i < 4; i++){
      int row = wv*16 + lg*4 + i;
      sS2[row*256 + (col ^ ((row & 7) << 3))] = f2bf(acc[ct][i] + bb);
    }
  }
}

// phase-2 body: compute 8 row-frags x 2 col-frags of S3 for columns pass*256+wv*32+{0,16}+lr
#define PHASE2(PASS, ACC)                                                               \
  {                                                                                     \
    _Pragma("unroll")                                                                   \
    for (int s = 0; s < 8; s++){                                                        \
      const int kk = s*32 + lg*8;                                                       \
      bf16x8 b0 = *reinterpret_cast<const bf16x8*>(                                     \
          W3bf + (size_t)((PASS)*256 + wv*32 + 0 + lr)*512 + 256 + kk);                 \
      bf16x8 b1 = *reinterpret_cast<const bf16x8*>(                                     \
          W3bf + (size_t)((PASS)*256 + wv*32 + 16 + lr)*512 + 256 + kk);                \
      _Pragma("unroll")                                                                 \
      for (int rf = 0; rf < 8; rf++){                                                   \
        int row = rf*16 + lr;                                                           \
        bf16x8 a = *reinterpret_cast<const bf16x8*>(                                    \
            &sS2[row*256 + (kk ^ ((row & 7) << 3))]);                                   \
        ACC[rf][0] = __builtin_amdgcn_mfma_f32_16x16x32_bf16(a, b0, ACC[rf][0], 0,0,0); \
        ACC[rf][1] = __builtin_amdgcn_mfma_f32_16x16x32_bf16(a, b1, ACC[rf][1], 0,0,0); \
      }                                                                                 \
    }                                                                                   \
  }

// ---------------- enc3: S2 -> S3 (+U) -> per-block BN2 channel partials ----------------
__global__ __launch_bounds__(512) void enc3_kernel(const float* __restrict__ xyz,
                                                   const int* __restrict__ knnIdx,
                                                   const float4* __restrict__ F1c,
                                                   const ushortT* __restrict__ W2bf,
                                                   const float* __restrict__ b2,
                                                   const ushortT* __restrict__ W3bf,
                                                   const float* __restrict__ U,
                                                   float* __restrict__ P2sum,
                                                   float* __restrict__ P2sq){
  __shared__ ushortT sS2[128 * 256];         // 64 KB swizzled
  const int blk = blockIdx.x;                // 2048 tiles of 128 rows
  const int t = threadIdx.x, lane = t & 63, wv = t >> 6;
  const int lr = lane & 15, lg = lane >> 4;
  phaseA_s2(xyz, knnIdx, F1c, W2bf, b2, sS2, blk, wv, lr, lg);
  __syncthreads();
#pragma unroll
  for (int pass = 0; pass < 2; pass++){
    f32x4 acc[8][2];
#pragma unroll
    for (int rf = 0; rf < 8; rf++){ acc[rf][0] = (f32x4){0,0,0,0}; acc[rf][1] = (f32x4){0,0,0,0}; }
    PHASE2(pass, acc)
#pragma unroll
    for (int ct = 0; ct < 2; ct++){
      int col = pass*256 + wv*32 + ct*16 + lr;
      float s = 0.f, q = 0.f;
#pragma unroll
      for (int rf = 0; rf < 8; rf++){
        float uv = U[(size_t)(blk*4 + (rf >> 1)) * 512 + col];
#pragma unroll
        for (int i = 0; i < 4; i++){
          float v = acc[rf][ct][i] + uv;
          s += v; q += v * v;
        }
      }
      s += __shfl_xor(s, 16); s += __shfl_xor(s, 32);
      q += __shfl_xor(q, 16); q += __shfl_xor(q, 32);
      if (lg == 0){
        P2sum[(size_t)blk * 512 + col] = s;
        P2sq [(size_t)blk * 512 + col] = q;
      }
    }
  }
}

// ---------------- BN finalize (BN2): one block per channel ----------------
__global__ __launch_bounds__(256) void fin_kernel(const float* __restrict__ Psum,
                                                  const float* __restrict__ Psq,
                                                  int nPart, int C, float invN,
                                                  const float* __restrict__ g,
                                                  const float* __restrict__ be,
                                                  float* __restrict__ scale,
                                                  float* __restrict__ shift){
  const int ch = blockIdx.x, t = threadIdx.x;
  float s = 0.f, q = 0.f;
  for (int i = t; i < nPart; i += 256){
    s += Psum[(size_t)i * C + ch];
    q += Psq [(size_t)i * C + ch];
  }
  __shared__ float ls[4], lq[4];
#pragma unroll
  for (int m = 32; m >= 1; m >>= 1){ s += __shfl_xor(s, m); q += __shfl_xor(q, m); }
  if ((t & 63) == 0){ ls[t >> 6] = s; lq[t >> 6] = q; }
  __syncthreads();
  if (t == 0){
    s = ls[0] + ls[1] + ls[2] + ls[3];
    q = lq[0] + lq[1] + lq[2] + lq[3];
    float mu = s * invN;
    float var = q * invN - mu * mu;
    float sc = rsqrtf(var + 1e-5f) * g[ch];
    scale[ch] = sc;
    shift[ch] = be[ch] - mu * sc;
  }
}

// ---------------- enc4: S2 -> S3(regs) -> bn2relu -> H(LDS, reusing S2 buf) -> W4 -> max ----
__global__ __launch_bounds__(512) void enc4_kernel(const float* __restrict__ xyz,
                                                   const int* __restrict__ knnIdx,
                                                   const float4* __restrict__ F1c,
                                                   const ushortT* __restrict__ W2bf,
                                                   const float* __restrict__ b2,
                                                   const ushortT* __restrict__ W3bf,
                                                   const float* __restrict__ U,
                                                   const float* __restrict__ scale2,
                                                   const float* __restrict__ shift2,
                                                   const ushortT* __restrict__ W4bf,
                                                   const float* __restrict__ b4,
                                                   float* __restrict__ feat){
  __shared__ ushortT sS2[128 * 256];         // 64 KB: S2, later reused as H
  __shared__ float s_sc[512], s_sh[512];
  const int blk = blockIdx.x;                // 2048 tiles of 128 rows
  const int t = threadIdx.x, lane = t & 63, wv = t >> 6;
  const int lr = lane & 15, lg = lane >> 4;
  if (t < 512){ s_sc[t] = scale2[t]; s_sh[t] = shift2[t]; }
  phaseA_s2(xyz, knnIdx, F1c, W2bf, b2, sS2, blk, wv, lr, lg);
  __syncthreads();
  // phase 2: both column passes, acc held in registers
  f32x4 acc0[8][2], acc1[8][2];
#pragma unroll
  for (int rf = 0; rf < 8; rf++){
    acc0[rf][0] = (f32x4){0,0,0,0}; acc0[rf][1] = (f32x4){0,0,0,0};
    acc1[rf][0] = (f32x4){0,0,0,0}; acc1[rf][1] = (f32x4){0,0,0,0};
  }
  PHASE2(0, acc0)
  PHASE2(1, acc1)
  __syncthreads();                           // everyone done reading S2
  f32x4 accF[8];
#pragma unroll
  for (int rf = 0; rf < 8; rf++) accF[rf] = (f32x4){0,0,0,0};
  // ---- K half 0: H cols 0..255 from acc0 ----
#pragma unroll
  for (int ct = 0; ct < 2; ct++){
    int colh = wv*32 + ct*16 + lr;           // local col in half == global col (pass 0)
#pragma unroll
    for (int rf = 0; rf < 8; rf++){
      float uv = U[(size_t)(blk*4 + (rf >> 1)) * 512 + colh];
#pragma unroll
      for (int i = 0; i < 4; i++){
        int row = rf*16 + lg*4 + i;
        float v = acc0[rf][ct][i] + uv;
        sS2[row*256 + (colh ^ ((row & 7) << 3))] =
            f2bf(fmaxf(fmaf(v, s_sc[colh], s_sh[colh]), 0.f));
      }
    }
  }
  __syncthreads();
#pragma unroll
  for (int s = 0; s < 8; s++){
    const int kk = s*32 + lg*8;
    bf16x8 b = *reinterpret_cast<const bf16x8*>(W4bf + (size_t)(wv*16 + lr)*512 + kk);
#pragma unroll
    for (int rf = 0; rf < 8; rf++){
      int row = rf*16 + lr;
      bf16x8 a = *reinterpret_cast<const bf16x8*>(&sS2[row*256 + (kk ^ ((row & 7) << 3))]);
      accF[rf] = __builtin_amdgcn_mfma_f32_16x16x32_bf16(a, b, accF[rf], 0, 0, 0);
    }
  }
  __syncthreads();
  // ---- K half 1: H cols 256..511 from acc1 ----
#pragma unroll
  for (int ct = 0; ct < 2; ct++){
    int colh = wv*32 + ct*16 + lr;
    int col  = 256 + colh;
#pragma unroll
    for (int rf = 0; rf < 8; rf++){
      float uv = U[(size_t)(blk*4 + (rf >> 1)) * 512 + col];
#pragma unroll
      for (int i = 0; i < 4; i++){
        int row = rf*16 + lg*4 + i;
        float v = acc1[rf][ct][i] + uv;
        sS2[row*256 + (colh ^ ((row & 7) << 3))] =
            f2bf(fmaxf(fmaf(v, s_sc[col], s_sh[col]), 0.f));
      }
    }
  }
  __syncthreads();
#pragma unroll
  for (int s = 0; s < 8; s++){
    const int kk = s*32 + lg*8;
    bf16x8 b = *reinterpret_cast<const bf16x8*>(W4bf + (size_t)(wv*16 + lr)*512 + 256 + kk);
#pragma unroll
    for (int rf = 0; rf < 8; rf++){
      int row = rf*16 + lr;
      bf16x8 a = *reinterpret_cast<const bf16x8*>(&sS2[row*256 + (kk ^ ((row & 7) << 3))]);
      accF[rf] = __builtin_amdgcn_mfma_f32_16x16x32_bf16(a, b, accF[rf], 0, 0, 0);
    }
  }
  // ---- epilogue: group-max (group = 32 rows = 2 row-frags) ----
  const float bb4 = b4[wv*16 + lr];
#pragma unroll
  for (int gl = 0; gl < 4; gl++){
    float m = -3.0e38f;
#pragma unroll
    for (int i = 0; i < 4; i++){
      m = fmaxf(m, accF[2*gl    ][i]);
      m = fmaxf(m, accF[2*gl + 1][i]);
    }
    m = fmaxf(m, __shfl_xor(m, 16));
    m = fmaxf(m, __shfl_xor(m, 32));
    if (lg == 0)
      feat[((size_t)blk*4 + gl)*128 + wv*16 + lr] = m + bb4;
  }
}

extern "C" void kernel_launch(void* const* d_in, const int* in_sizes, int n_in,
                              void* d_out, int out_size, void* d_ws, size_t ws_size,
                              hipStream_t stream){
  const float* xyz = (const float*)d_in[0];
  const float* W1  = (const float*)d_in[1];
  const float* b1  = (const float*)d_in[2];
  const float* g1  = (const float*)d_in[3];
  const float* be1 = (const float*)d_in[4];
  const float* W2  = (const float*)d_in[5];
  const float* b2  = (const float*)d_in[6];
  const float* W3  = (const float*)d_in[7];
  const float* b3  = (const float*)d_in[8];
  const float* g2  = (const float*)d_in[9];
  const float* be2 = (const float*)d_in[10];
  const float* W4  = (const float*)d_in[11];
  const float* b4  = (const float*)d_in[12];

  float* out = (float*)d_out;
  float* center = out;                         // (16,512,3)
  float* feat   = out + (size_t)B_ * G_ * 3;   // (16,512,128)

  char* p = (char*)d_ws;
  size_t used = 0;
  auto alloc = [&](size_t bytes) -> char* {
    char* r = p + used; used += (bytes + 255) & ~(size_t)255; return r;
  };
  int*     knnIdx = (int*)    alloc((size_t)R_ * 4);           // 1 MB
  ushortT* W2bf   = (ushortT*)alloc(32768 * 2);
  ushortT* W3bf   = (ushortT*)alloc(262144 * 2);
  ushortT* W4bf   = (ushortT*)alloc(65536 * 2);
  float4*  F1c    = (float4*) alloc(128 * 16);
  float*   Mpart  = (float*)  alloc(256 * 9 * 4);
  ushortT* fg     = (ushortT*)alloc((size_t)M_ * 256 * 2);     // 4 MB
  float*   U      = (float*)  alloc((size_t)M_ * 512 * 4);     // 16 MB
  float*   P2sum  = (float*)  alloc((size_t)2048 * 512 * 4);   // 4 MB
  float*   P2sq   = (float*)  alloc((size_t)2048 * 512 * 4);   // 4 MB
  float*   scale2 = (float*)  alloc(512 * 4);
  float*   shift2 = (float*)  alloc(512 * 4);

  cast3_kernel  <<<dim3(1024), dim3(256),  0, stream>>>(W2, W3, W4, W2bf, W3bf, W4bf);
  fps_kernel    <<<dim3(B_),   dim3(1024), 0, stream>>>(xyz, center);
  knn_kernel    <<<dim3(M_),   dim3(256),  0, stream>>>(xyz, center, knnIdx);
  moments_kernel<<<dim3(256),  dim3(256),  0, stream>>>(xyz, knnIdx, Mpart);
  prep1_kernel  <<<dim3(1),    dim3(128),  0, stream>>>(Mpart, W1, b1, g1, be1, F1c);
  f2g_kernel    <<<dim3(4096), dim3(256),  0, stream>>>(xyz, knnIdx, F1c, W2bf, b2, fg);
  u_kernel      <<<dim3(512),  dim3(256),  0, stream>>>(fg, W3bf, b3, U);
  enc3_kernel   <<<dim3(2048), dim3(512),  0, stream>>>(xyz, knnIdx, F1c, W2bf, b2, W3bf, U, P2sum, P2sq);
  fin_kernel    <<<dim3(512),  dim3(256),  0, stream>>>(P2sum, P2sq, 2048, 512, 1.0f/(float)R_, g2, be2, scale2, shift2);
  enc4_kernel   <<<dim3(2048), dim3(512),  0, stream>>>(xyz, knnIdx, F1c, W2bf, b2, W3bf, U,
                                                        scale2, shift2, W4bf, b4, feat);
}